// Round 6
// baseline (209.664 us; speedup 1.0000x reference)
//
#include <hip/hip_runtime.h>
#include <math.h>

#define IMG_H 512
#define IMG_W 512
#define N_IMG 96            // 32 * 3
#define TW 64               // tile width (output cols)
#define TH 16               // tile height (output rows)
#define KS 11
#define IN_ROWS 26          // TH + 10
#define NUNITS (IN_ROWS * 16)   // 416 horizontal-conv units (4 px each)
#define PLANE 1690          // 26 * 65 (odd stride 65 -> conflict-free)
#define NBLOCKS (N_IMG * (IMG_W / TW) * (IMG_H / TH))   // 24576
#define TOTAL_N 25165824.0  // 32*3*512*512

// Round-6 design change: STREAMING accumulation in both stages so peak
// register liveness is ~45 floats by construction (round 5: VGPR_Count=52
// vs ~55-70 wanted -> compiler rematerialized, ~2x VALU overhead).
//  - Stage 1: walk the 20-float window chunk by chunk (float4); each element
//    (statically known to be used, ge in [3,16]) immediately contributes its
//    5-map FMAs to the 20 accumulators. Taps j = ge-3-k are compile-time.
//  - Stage 2: walk 14 LDS rows; each row's 5 map values immediately feed the
//    20 accumulators (j = i-k compile-time).
//  - Division replaced by v_rcp_f32 (__builtin_amdgcn_rcpf), ~1e-5 rel err.
// LDS plane layout unchanged (odd stride 65 -> 2-way banks, free).

__global__ __launch_bounds__(256, 4) void ssim_tile_kernel(
    const float* __restrict__ pred, const float* __restrict__ targ,
    const float* __restrict__ k2d, float* __restrict__ partial)
{
    __shared__ float H[5][PLANE];
    __shared__ float wsum[4];

    const int tid = threadIdx.x;
    const int bid = blockIdx.x;
    const int img = bid >> 8;          // 256 tiles per image
    const int tin = bid & 255;
    const int ty  = tin >> 3;
    const int tx  = tin & 7;
    const int y0  = ty * TH;
    const int x0  = tx * TW;

    // exact 1D gaussian from the 2D kernel: k2d[5][j] = g5 * g[j], k2d[5][5] = g5^2
    float g[KS];
    {
        const float inv = rsqrtf(k2d[5 * KS + 5]);
        #pragma unroll
        for (int j = 0; j < KS; ++j) g[j] = k2d[5 * KS + j] * inv;
    }

    const float* __restrict__ Pimg = pred + (size_t)img * (IMG_H * IMG_W);
    const float* __restrict__ Timg = targ + (size_t)img * (IMG_H * IMG_W);

    // ---- stage 1: horizontal 11-tap pass (streaming), global -> LDS ----
    #pragma unroll
    for (int b = 0; b < 2; ++b) {
        const int u = tid + (b << 8);
        if (u < NUNITS) {
            const int r    = u >> 4;
            const int cg   = u & 15;
            const int gr   = y0 - 5 + r;
            const int col0 = x0 + (cg << 2) - 8;   // 16B-aligned window start
            const bool rowok = ((unsigned)gr < (unsigned)IMG_H);
            const bool fast  = rowok && (col0 >= 0) && (col0 + 20 <= IMG_W);
            const float* rowP = Pimg + (size_t)(rowok ? gr : 0) * IMG_W;
            const float* rowT = Timg + (size_t)(rowok ? gr : 0) * IMG_W;

            float ax[4], ay[4], axx[4], ayy[4], axy[4];
            #pragma unroll
            for (int k = 0; k < 4; ++k) {
                ax[k] = 0.f; ay[k] = 0.f; axx[k] = 0.f; ayy[k] = 0.f; axy[k] = 0.f;
            }

            #pragma unroll
            for (int q = 0; q < 5; ++q) {
                float pe[4], te[4];
                if (fast) {
                    const float4 vp = *(const float4*)(rowP + col0 + 4 * q);
                    const float4 vt = *(const float4*)(rowT + col0 + 4 * q);
                    pe[0] = vp.x; pe[1] = vp.y; pe[2] = vp.z; pe[3] = vp.w;
                    te[0] = vt.x; te[1] = vt.y; te[2] = vt.z; te[3] = vt.w;
                } else {
                    #pragma unroll
                    for (int e = 0; e < 4; ++e) {
                        const int ge = 4 * q + e;
                        if (ge >= 3 && ge <= 16) {
                            const int c  = col0 + ge;
                            const int cc = min(max(c, 0), IMG_W - 1);
                            const bool ok = rowok && (c >= 0) && (c < IMG_W);
                            const float pv = rowP[cc];
                            const float tv = rowT[cc];
                            pe[e] = ok ? pv : 0.0f;
                            te[e] = ok ? tv : 0.0f;
                        } else {
                            pe[e] = 0.0f; te[e] = 0.0f;
                        }
                    }
                }
                // fan each used element into the 20 accumulators
                #pragma unroll
                for (int e = 0; e < 4; ++e) {
                    const int ge = 4 * q + e;          // compile-time
                    if (ge >= 3 && ge <= 16) {         // used window elems
                        const float pv = pe[e];
                        const float tv = te[e];
                        const float pp = pv * pv;
                        const float tt = tv * tv;
                        const float pt = pv * tv;
                        #pragma unroll
                        for (int k = 0; k < 4; ++k) {
                            const int j = ge - 3 - k;  // compile-time tap
                            if (j >= 0 && j < KS) {
                                ax [k] = fmaf(g[j], pv, ax [k]);
                                ay [k] = fmaf(g[j], tv, ay [k]);
                                axx[k] = fmaf(g[j], pp, axx[k]);
                                ayy[k] = fmaf(g[j], tt, ayy[k]);
                                axy[k] = fmaf(g[j], pt, axy[k]);
                            }
                        }
                    }
                }
            }

            const int wb = r * 65 + (cg << 2);
            #pragma unroll
            for (int e = 0; e < 4; ++e) {
                H[0][wb + e] = ax[e];
                H[1][wb + e] = ay[e];
                H[2][wb + e] = axx[e];
                H[3][wb + e] = ayy[e];
                H[4][wb + e] = axy[e];
            }
        }
    }
    __syncthreads();

    // ---- stage 2: vertical 11-tap pass (streaming) + SSIM formula ----
    const int col  = tid & 63;
    const int rg   = tid >> 6;
    const int base = rg * 4 * 65 + col;

    float mx[4], my[4], sxx[4], syy[4], sxy[4];
    #pragma unroll
    for (int k = 0; k < 4; ++k) {
        mx[k] = 0.f; my[k] = 0.f; sxx[k] = 0.f; syy[k] = 0.f; sxy[k] = 0.f;
    }

    #pragma unroll
    for (int i = 0; i < 14; ++i) {
        const int idx = base + i * 65;
        const float hx  = H[0][idx];
        const float hy  = H[1][idx];
        const float hxx = H[2][idx];
        const float hyy = H[3][idx];
        const float hxy = H[4][idx];
        #pragma unroll
        for (int k = 0; k < 4; ++k) {
            const int j = i - k;                   // compile-time tap
            if (j >= 0 && j < KS) {
                mx [k] = fmaf(g[j], hx,  mx [k]);
                my [k] = fmaf(g[j], hy,  my [k]);
                sxx[k] = fmaf(g[j], hxx, sxx[k]);
                syy[k] = fmaf(g[j], hyy, syy[k]);
                sxy[k] = fmaf(g[j], hxy, sxy[k]);
            }
        }
    }

    const float C1 = 1.0e-4f;   // (0.01*1)^2
    const float C2 = 9.0e-4f;   // (0.03*1)^2
    float lsum = 0.0f;
    #pragma unroll
    for (int k = 0; k < 4; ++k) {
        const float mx2 = mx[k] * mx[k];
        const float my2 = my[k] * my[k];
        const float mxy = mx[k] * my[k];
        const float num = (2.0f * mxy + C1) * (2.0f * (sxy[k] - mxy) + C2);
        const float den = (mx2 + my2 + C1) * ((sxx[k] - mx2) + (syy[k] - my2) + C2);
        lsum = fmaf(num, __builtin_amdgcn_rcpf(den), lsum);
    }

    // ---- block reduction ----
    #pragma unroll
    for (int off = 32; off > 0; off >>= 1)
        lsum += __shfl_down(lsum, off, 64);

    const int lane = tid & 63;
    const int wid  = tid >> 6;
    if (lane == 0) wsum[wid] = lsum;
    __syncthreads();
    if (tid == 0)
        partial[bid] = wsum[0] + wsum[1] + wsum[2] + wsum[3];
}

// ---------------- final reduction ----------------
__global__ __launch_bounds__(1024) void ssim_reduce_kernel(
    const float* __restrict__ partial, int n, float* __restrict__ out)
{
    const int tid = threadIdx.x;
    double s = 0.0;
    for (int i = tid; i < n; i += 1024) s += (double)partial[i];

    #pragma unroll
    for (int off = 32; off > 0; off >>= 1)
        s += __shfl_down(s, off, 64);

    __shared__ double dsum[16];
    const int lane = tid & 63;
    const int wid  = tid >> 6;
    if (lane == 0) dsum[wid] = s;
    __syncthreads();
    if (tid == 0) {
        double total = 0.0;
        #pragma unroll
        for (int w = 0; w < 16; ++w) total += dsum[w];
        out[0] = (float)(1.0 - total / TOTAL_N);
    }
}

extern "C" void kernel_launch(void* const* d_in, const int* in_sizes, int n_in,
                              void* d_out, int out_size, void* d_ws, size_t ws_size,
                              hipStream_t stream) {
    const float* pred = (const float*)d_in[0];
    const float* targ = (const float*)d_in[1];
    const float* k2d  = (const float*)d_in[2];
    float* out = (float*)d_out;
    float* ws  = (float*)d_ws;   // NBLOCKS partial sums

    ssim_tile_kernel<<<NBLOCKS, 256, 0, stream>>>(pred, targ, k2d, ws);
    ssim_reduce_kernel<<<1, 1024, 0, stream>>>(ws, NBLOCKS, out);
}